// Round 1
// baseline (99.673 us; speedup 1.0000x reference)
//
#include <hip/hip_runtime.h>
#include <math.h>

#define B 512
#define P 4
#define A 32
#define T 8
#define NK 21

// ---------------------------------------------------------------------------
// Kernel 1: one block per (t,b,p), 96 threads = (a,d) element each.
// Computes score[t,b,p,a,d] (to ws) and log_p_graph[t,b,p] (LDS reduction).
// logsumexp max is closed-form: k* = round(x) since logits = -(x-k)^2 * c.
// ---------------------------------------------------------------------------
__global__ void k1_score_logp(const float* __restrict__ xt,      // (B*A,3)
                              const float* __restrict__ perm,    // (B*P*A,3)
                              const float* __restrict__ sigmas,  // (B,)
                              const float* __restrict__ shifts,  // (T,B*P,3)
                              float* __restrict__ score,         // (T*B*P, 96)
                              float* __restrict__ logp_graph)    // (T*B*P,)
{
    __shared__ float sdata[128];
    const int bid = blockIdx.x;          // ((t*B + b)*P + p)
    const int p  = bid % P;
    const int tb = bid / P;
    const int b  = tb % B;
    const int t  = tb / B;
    const int j  = threadIdx.x;          // 0..95
    const int a  = j / 3;
    const int d  = j % 3;

    const float sig = sigmas[b];
    const float c   = 1.0f / (2.0f * sig * sig);   // inv2s2

    const float xv = xt[(b * A + a) * 3 + d];
    const float pv = perm[((b * P + p) * A + a) * 3 + d];
    const float sv = shifts[(t * (B * P) + b * P + p) * 3 + d];

    float s  = pv + sv + 1.0f;
    float ap = s - floorf(s);            // (perm + shift + 1) % 1
    float x  = xv - ap;

    // max logit at nearest integer k (x in (-1,1) so k* within [-10,10])
    float kstar = roundf(x);
    float dx0   = x - kstar;
    float m     = -dx0 * dx0 * c;

    float sume = 0.0f, sums = 0.0f;
    #pragma unroll
    for (int ki = 0; ki < NK; ++ki) {
        float kf = (float)(ki - 10);
        float dx = x - kf;
        float e  = expf(c * (dx0 * dx0 - dx * dx));   // exp(logit - m)
        sume += e;
        sums += e * (kf - x);
    }
    float logp = m + logf(sume);
    score[bid * 96 + j] = sums / sume * (2.0f * c);   // / sigma^2

    // block reduction of logp over 96 elements
    sdata[j] = logp;
    if (j < 32) sdata[96 + j] = 0.0f;
    __syncthreads();
    for (int str = 64; str > 0; str >>= 1) {
        if (j < str) sdata[j] += sdata[j + str];
        __syncthreads();
    }
    if (j == 0) logp_graph[bid] = sdata[0];
}

// ---------------------------------------------------------------------------
// Kernel 2: per-b softmax over the 32 (t,p) values of log_p_graph.
// One 32-lane group per b; shuffle reduction (width 32 inside wave64).
// weights[t,b,p] = softmax over lt[b, t*P+p].
// ---------------------------------------------------------------------------
__global__ void k2_weights(const float* __restrict__ logp_graph,
                           float* __restrict__ weights)
{
    const int g = blockIdx.x * blockDim.x + threadIdx.x;  // 0 .. B*32-1
    const int b = g >> 5;
    const int i = g & 31;          // t*P + p
    const int t = i / P;
    const int p = i % P;

    float v = logp_graph[(t * B + b) * P + p];
    float mx = v;
    #pragma unroll
    for (int o = 16; o > 0; o >>= 1) mx = fmaxf(mx, __shfl_xor(mx, o, 32));
    float e = expf(v - mx);
    float sum = e;
    #pragma unroll
    for (int o = 16; o > 0; o >>= 1) sum += __shfl_xor(sum, o, 32);
    weights[(t * B + b) * P + p] = e / sum;
}

// ---------------------------------------------------------------------------
// Kernel 3: tar[b,p,a,d] = sum_t weights[t,b,p] * score[t,b,p,a,d];
// scatter-add into out[b*A + helper[b,p*A+a], d].
// ---------------------------------------------------------------------------
__global__ void k3_tar_scatter(const float* __restrict__ score,
                               const float* __restrict__ weights,
                               const int* __restrict__ helper,   // (B*P*A,)
                               float* __restrict__ out)          // (B*A,3)
{
    const int g = blockIdx.x * blockDim.x + threadIdx.x;
    if (g >= B * P * A * 3) return;
    const int d  = g % 3;
    const int r  = g / 3;          // (b*P+p)*A + a
    const int a  = r % A;
    const int bp = r / A;          // b*P + p
    const int p  = bp % P;
    const int b  = bp / P;

    float acc = 0.0f;
    #pragma unroll
    for (int t = 0; t < T; ++t) {
        const int idx = (t * B + b) * P + p;
        acc += weights[idx] * score[idx * 96 + a * 3 + d];
    }
    const int row = b * A + helper[bp * A + a];
    atomicAdd(&out[row * 3 + d], acc);
}

// ---------------------------------------------------------------------------
extern "C" void kernel_launch(void* const* d_in, const int* in_sizes, int n_in,
                              void* d_out, int out_size, void* d_ws, size_t ws_size,
                              hipStream_t stream)
{
    const float* xt     = (const float*)d_in[0];  // frac_coords_t
    const float* perm   = (const float*)d_in[1];  // permuted_frac_coords
    const float* sigmas = (const float*)d_in[2];  // sigmas
    const float* shifts = (const float*)d_in[3];  // random_shifts
    const int*   helper = (const int*)d_in[4];    // helper_permuted_indices
    float* out = (float*)d_out;

    float* score   = (float*)d_ws;                       // T*B*P*96 floats
    float* logp    = score + (size_t)T * B * P * 96;     // T*B*P floats
    float* weights = logp + (size_t)T * B * P;           // T*B*P floats

    hipMemsetAsync(d_out, 0, (size_t)out_size * sizeof(float), stream);

    k1_score_logp<<<T * B * P, 96, 0, stream>>>(xt, perm, sigmas, shifts, score, logp);
    k2_weights<<<(B * 32) / 256, 256, 0, stream>>>(logp, weights);
    k3_tar_scatter<<<(B * P * A * 3 + 255) / 256, 256, 0, stream>>>(score, weights, helper, out);
}

// Round 2
// 72.169 us; speedup vs baseline: 1.3811x; 1.3811x over previous
//
#include <hip/hip_runtime.h>
#include <math.h>

#define B 512
#define P 4
#define A 32
#define T 8
#define NK 21
#define TPB 512          // 512 threads = 8 waves per block, one block per b
#define SC_LD 97         // padded leading dim for sc to kill bank conflicts

// ---------------------------------------------------------------------------
// Fully fused: one block per batch b.
//   phase 1: each thread computes 6 elements (fixed tp = t*P+p, varying j=a*3+d):
//            score -> LDS sc[tp][j], logp partial -> register
//   phase 2: reduce logp over j per tp; 32-lane shuffle softmax -> warr[tp]
//   phase 3: tar[p,a,d] = sum_t warr * sc ; LDS-atomic segment sum into acc
//            (all scatter targets for batch b are rows [b*A,(b+1)*A) -- block-local!)
//   phase 4: coalesced store of 96 floats
// No workspace, no global atomics, no memset.
// ---------------------------------------------------------------------------
__global__ __launch_bounds__(TPB) void tgd_fused(
    const float* __restrict__ xt,      // (B*A,3)   = (B,96) flat
    const float* __restrict__ perm,    // (B*P*A,3) = (B,384) flat
    const float* __restrict__ sigmas,  // (B,)
    const float* __restrict__ shifts,  // (T,B*P,3)
    const int*   __restrict__ helper,  // (B*P*A,)  = (B,128) flat
    float*       __restrict__ out)     // (B*A,3)   = (B,96) flat
{
    __shared__ float sc[32 * SC_LD];   // [tp][j], padded: conflict-free r/w
    __shared__ float lpp[16][32];      // logp partials [m][tp]
    __shared__ float warr[32];         // softmax weights per tp
    __shared__ float acc[96];          // segment-sum accumulator (A*3)

    const int b   = blockIdx.x;
    const int tid = threadIdx.x;
    const int tp  = tid & 31;          // t*P + p  (fixed per thread)
    const int m   = tid >> 5;          // 0..15
    const int t   = tp >> 2;
    const int p   = tp & 3;

    const float sig = sigmas[b];
    const float c   = 1.0f / (2.0f * sig * sig);   // inv2s2
    const float two_c = 2.0f * c;                  // 1/sigma^2

    float lp_local = 0.0f;
    #pragma unroll
    for (int k = 0; k < 6; ++k) {
        const int j = m + 16 * k;      // 0..95, each thread covers 6 j's
        const int d = j % 3;

        const float xv = xt[b * 96 + j];
        const float pv = perm[b * 384 + p * 96 + j];
        const float sv = shifts[(t * (B * P) + b * P + p) * 3 + d];

        float s  = pv + sv + 1.0f;
        float ap = s - floorf(s);                  // (perm+shift+1) % 1
        float x  = xv - ap;                        // in (-1,1)

        // closed-form logsumexp max: k* = round(x)
        float kstar = roundf(x);
        float dx0   = x - kstar;
        float m0    = -dx0 * dx0 * c;

        float sume = 0.0f, sums = 0.0f;
        #pragma unroll
        for (int ki = 0; ki < NK; ++ki) {
            float dx = x - (float)(ki - 10);
            float e  = __expf(c * (dx0 * dx0 - dx * dx));  // exp(logit - max)
            sume += e;
            sums -= e * dx;                        // e * (k - x)
        }
        lp_local += m0 + __logf(sume);
        sc[tp * SC_LD + j] = (sums / sume) * two_c;
    }

    lpp[m][tp] = lp_local;
    if (tid >= 32 && tid < 128) acc[tid - 32] = 0.0f;
    __syncthreads();

    if (tid < 32) {
        float v = 0.0f;
        #pragma unroll
        for (int mm = 0; mm < 16; ++mm) v += lpp[mm][tid];
        // softmax over the 32 (t,p) values of this b
        float mx = v;
        #pragma unroll
        for (int o = 16; o > 0; o >>= 1) mx = fmaxf(mx, __shfl_xor(mx, o, 32));
        float e = __expf(v - mx);
        float sum = e;
        #pragma unroll
        for (int o = 16; o > 0; o >>= 1) sum += __shfl_xor(sum, o, 32);
        warr[tid] = e / sum;
    }
    __syncthreads();

    if (tid < 384) {                   // one (p,a,d) item per thread
        const int pp = tid / 96;
        const int j  = tid % 96;
        const int a  = j / 3;
        const int d  = j % 3;
        float val = 0.0f;
        #pragma unroll
        for (int tt = 0; tt < T; ++tt) {
            const int wi = tt * 4 + pp;
            val += warr[wi] * sc[wi * SC_LD + j];
        }
        const int h = helper[b * 128 + pp * 32 + a];
        atomicAdd(&acc[h * 3 + d], val);
    }
    __syncthreads();

    if (tid < 96) out[b * 96 + tid] = acc[tid];
}

// ---------------------------------------------------------------------------
extern "C" void kernel_launch(void* const* d_in, const int* in_sizes, int n_in,
                              void* d_out, int out_size, void* d_ws, size_t ws_size,
                              hipStream_t stream)
{
    const float* xt     = (const float*)d_in[0];
    const float* perm   = (const float*)d_in[1];
    const float* sigmas = (const float*)d_in[2];
    const float* shifts = (const float*)d_in[3];
    const int*   helper = (const int*)d_in[4];
    float* out = (float*)d_out;

    tgd_fused<<<B, TPB, 0, stream>>>(xt, perm, sigmas, shifts, helper, out);
}

// Round 3
// 67.054 us; speedup vs baseline: 1.4865x; 1.0763x over previous
//
#include <hip/hip_runtime.h>
#include <math.h>

#define B 512
#define P 4
#define A 32
#define T 8
#define TPB 512          // 8 waves per block, one block per b
#define SC_LD 97         // padded leading dim: conflict-free LDS r/w

// ---------------------------------------------------------------------------
// Fully fused, one block per batch b. Closed-form 5-term logsumexp:
// logits_k = -(x-k)^2 * c is maximized at k* = round(x); terms at |q|>=3
// from k* are <= e^-12 relative (c >= 2, |dx0| <= 0.5) -> drop them.
// e_q = exp(c*(2q*dx0 - q^2)), all exponents <= 0 (no overflow at any sigma).
//   sume = 1 + e1 + em1 + e2 + em2
//   sumq = (e1 - em1) + 2*(e2 - em2)
//   score = 2c * (sumq/sume - dx0)
//   logp  = -dx0^2*c + log(sume)
// ---------------------------------------------------------------------------
__global__ __launch_bounds__(TPB) void tgd_fused(
    const float* __restrict__ xt,      // (B*A,3)   = (B,96) flat
    const float* __restrict__ perm,    // (B*P*A,3) = (B,384) flat
    const float* __restrict__ sigmas,  // (B,)
    const float* __restrict__ shifts,  // (T,B*P,3)
    const int*   __restrict__ helper,  // (B*P*A,)  = (B,128) flat
    float*       __restrict__ out)     // (B*A,3)   = (B,96) flat
{
    __shared__ float sc[32 * SC_LD];   // [tp][j]
    __shared__ float lpp[16][32];      // logp partials [m][tp]
    __shared__ float warr[32];         // softmax weights per tp
    __shared__ float acc[96];          // block-local segment-sum (A*3)

    const int b   = blockIdx.x;
    const int tid = threadIdx.x;
    const int tp  = tid & 31;          // t*P + p (fixed per thread)
    const int m   = tid >> 5;          // 0..15
    const int t   = tp >> 2;
    const int p   = tp & 3;

    const float sig = sigmas[b];
    const float c     = 1.0f / (2.0f * sig * sig);
    const float two_c = 2.0f * c;

    float lp_local = 0.0f;
    #pragma unroll
    for (int k = 0; k < 6; ++k) {
        const int j = m + 16 * k;      // 0..95
        const int d = j % 3;

        const float xv = xt[b * 96 + j];
        const float pv = perm[b * 384 + p * 96 + j];
        const float sv = shifts[(t * (B * P) + b * P + p) * 3 + d];

        float s  = pv + sv + 1.0f;
        float ap = s - floorf(s);                  // (perm+shift+1) % 1
        float x  = xv - ap;                        // (-1,1)

        float kstar = roundf(x);
        float dx0   = x - kstar;                   // [-0.5, 0.5]

        // 4 tail terms, exponents all <= 0
        float e1  = __expf(c * ( 2.0f * dx0 - 1.0f));
        float em1 = __expf(c * (-2.0f * dx0 - 1.0f));
        float e2  = __expf(c * ( 4.0f * dx0 - 4.0f));
        float em2 = __expf(c * (-4.0f * dx0 - 4.0f));

        float sume = 1.0f + e1 + em1 + e2 + em2;
        float sumq = (e1 - em1) + 2.0f * (e2 - em2);
        float inv  = 1.0f / sume;

        sc[tp * SC_LD + j] = two_c * (sumq * inv - dx0);
        lp_local += __logf(sume) - dx0 * dx0 * c;
    }

    lpp[m][tp] = lp_local;
    if (tid >= 32 && tid < 128) acc[tid - 32] = 0.0f;
    __syncthreads();

    if (tid < 32) {
        float v = 0.0f;
        #pragma unroll
        for (int mm = 0; mm < 16; ++mm) v += lpp[mm][tid];
        float mx = v;
        #pragma unroll
        for (int o = 16; o > 0; o >>= 1) mx = fmaxf(mx, __shfl_xor(mx, o, 32));
        float e = __expf(v - mx);
        float sum = e;
        #pragma unroll
        for (int o = 16; o > 0; o >>= 1) sum += __shfl_xor(sum, o, 32);
        warr[tid] = e / sum;
    }
    __syncthreads();

    if (tid < 384) {                   // one (p,a,d) per thread
        const int pp = tid / 96;
        const int j  = tid % 96;
        const int a  = j / 3;
        const int d  = j % 3;
        float val = 0.0f;
        #pragma unroll
        for (int tt = 0; tt < T; ++tt) {
            const int wi = tt * 4 + pp;
            val += warr[wi] * sc[wi * SC_LD + j];
        }
        const int h = helper[b * 128 + pp * 32 + a];
        atomicAdd(&acc[h * 3 + d], val);
    }
    __syncthreads();

    if (tid < 96) out[b * 96 + tid] = acc[tid];
}

// ---------------------------------------------------------------------------
extern "C" void kernel_launch(void* const* d_in, const int* in_sizes, int n_in,
                              void* d_out, int out_size, void* d_ws, size_t ws_size,
                              hipStream_t stream)
{
    const float* xt     = (const float*)d_in[0];
    const float* perm   = (const float*)d_in[1];
    const float* sigmas = (const float*)d_in[2];
    const float* shifts = (const float*)d_in[3];
    const int*   helper = (const int*)d_in[4];
    float* out = (float*)d_out;

    tgd_fused<<<B, TPB, 0, stream>>>(xt, perm, sigmas, shifts, helper, out);
}